// Round 10
// baseline (374.682 us; speedup 1.0000x reference)
//
#include <hip/hip_runtime.h>
#include <math.h>

#define NNODES 50000
#define NEDGES 800000
#define INDIM 256
#define HID 64
#define HEADS 4
#define OUTDIM 64
#define NEG_SLOPE 0.2f
#define NB ((NNODES + 1023) / 1024)   // 49 scan blocks

typedef __attribute__((ext_vector_type(4))) float f32x4;
typedef _Float16 __attribute__((ext_vector_type(8))) half8;

// ---------------- CSR build ----------------

__global__ __launch_bounds__(256) void hist_kernel(const int* __restrict__ dst,
                                                   int* __restrict__ deg) {
    int i = blockIdx.x * 256 + threadIdx.x;
    if (i < NEDGES) atomicAdd(&deg[dst[i]], 1);
}

__global__ __launch_bounds__(256) void bsum_kernel(const int* __restrict__ deg,
                                                   int* __restrict__ bsums) {
    int b = blockIdx.x, t = threadIdx.x;
    int base = b * 1024 + t * 4;
    int s = 0;
    #pragma unroll
    for (int e = 0; e < 4; ++e) { int i = base + e; if (i < NNODES) s += deg[i]; }
    #pragma unroll
    for (int o = 32; o; o >>= 1) s += __shfl_xor(s, o);
    __shared__ int ws[4];
    int lane = t & 63, wid = t >> 6;
    if (lane == 0) ws[wid] = s;
    __syncthreads();
    if (t == 0) bsums[b] = ws[0] + ws[1] + ws[2] + ws[3];
}

__global__ __launch_bounds__(256) void scan_write_kernel(const int* __restrict__ deg,
                                                         const int* __restrict__ bsums,
                                                         int* __restrict__ offs) {
    int b = blockIdx.x, t = threadIdx.x;
    int lane = t & 63, wid = t >> 6;
    int bv = (lane < b) ? bsums[lane] : 0;    // b <= NB-1 < 64
    #pragma unroll
    for (int o = 32; o; o >>= 1) bv += __shfl_xor(bv, o);  // block global offset
    int base = b * 1024 + t * 4;
    int v[4]; int tsum = 0;
    #pragma unroll
    for (int e = 0; e < 4; ++e) {
        int i = base + e;
        v[e] = (i < NNODES) ? deg[i] : 0;
        tsum += v[e];
    }
    int p = tsum;
    #pragma unroll
    for (int o = 1; o < 64; o <<= 1) { int u = __shfl_up(p, o); if (lane >= o) p += u; }
    __shared__ int ws[4];
    if (lane == 63) ws[wid] = p;
    __syncthreads();
    int woff = 0;
    for (int i = 0; i < wid; ++i) woff += ws[i];
    int run = bv + woff + p - tsum;           // exclusive prefix for this thread
    #pragma unroll
    for (int e = 0; e < 4; ++e) {
        int i = base + e;
        if (i < NNODES) { offs[i] = run; run += v[e]; }
    }
    if (b == 0 && t == 0) offs[NNODES] = NEDGES;
}

__global__ __launch_bounds__(256) void scatter_kernel(const int* __restrict__ src,
                                                      const int* __restrict__ dst,
                                                      const int* __restrict__ offs,
                                                      int* __restrict__ cursor,
                                                      int* __restrict__ ssorted) {
    int i = blockIdx.x * 256 + threadIdx.x;
    if (i < NEDGES) {
        int d = dst[i];
        int pos = offs[d] + atomicAdd(&cursor[d], 1);
        ssorted[pos] = src[i];
    }
}

// ---------------- weight transpose -> fp16 (both weights, one launch) ----

__global__ __launch_bounds__(256) void convert_wt_kernel(const float* __restrict__ W1,
                                                         _Float16* __restrict__ W1t,
                                                         const float* __restrict__ W2,
                                                         _Float16* __restrict__ W2t) {
    int idx = blockIdx.x * 256 + threadIdx.x;
    if (idx < 256 * 256) {
        int k = idx >> 8, n = idx & 255;
        W1t[n * 256 + k] = (_Float16)W1[idx];
    } else if (idx < 256 * 256 + 256 * 64) {
        int j = idx - 256 * 256;
        int k = j >> 6, n = j & 63;
        W2t[n * 256 + k] = (_Float16)W2[j];
    }
}

// ---------------- fp16 MFMA GEMM, LDS-free, 128x(BN) tile ----------------
// ELR=1 (BN=128): C node-major [M][256]; el/er NODE-MAJOR [M][4] so spmm1
//   reads all 4 heads' el with one 4B/lane gather off the same line.
// ELR=2 (BN=64): single head; per-wn partial dot + 1KB LDS combine.

template <int BN, bool AFP16, int ELR>
__global__ __launch_bounds__(256) void gemm_f16_kernel(
        const float* __restrict__ Af, const _Float16* __restrict__ Ah,
        const _Float16* __restrict__ Bt,
        _Float16* __restrict__ C,
        const float* __restrict__ al, const float* __restrict__ ar,
        float* __restrict__ el, float* __restrict__ er,
        int M, int N) {
    constexpr int K = 256;
    constexpr int NT = BN / 32;       // 16-wide n-tiles per wave
    int t = threadIdx.x;
    int lane = t & 63, w = t >> 6;
    int wm = w >> 1, wn = w & 1;
    int lr = lane & 15, quad = lane >> 4;
    int m0 = blockIdx.y * 128, n0 = blockIdx.x * BN;

    f32x4 acc[4][NT];
    #pragma unroll
    for (int i = 0; i < 4; ++i)
        #pragma unroll
        for (int j = 0; j < NT; ++j) acc[i][j] = (f32x4){0.f, 0.f, 0.f, 0.f};

    int arow[4];
    #pragma unroll
    for (int i = 0; i < 4; ++i) {
        int r = m0 + wm * 64 + i * 16 + lr;
        arow[i] = (r < M) ? r : (M - 1);
    }
    int brow[NT];
    #pragma unroll
    for (int j = 0; j < NT; ++j) brow[j] = n0 + wn * NT * 16 + j * 16 + lr;

    #pragma unroll
    for (int kk = 0; kk < K; kk += 32) {
        half8 a[4], b[NT];
        if (AFP16) {
            #pragma unroll
            for (int i = 0; i < 4; ++i)
                a[i] = *(const half8*)(Ah + (size_t)arow[i] * K + kk + quad * 8);
        } else {
            #pragma unroll
            for (int i = 0; i < 4; ++i) {
                const float* ap = Af + (size_t)arow[i] * K + kk + quad * 8;
                float4 f0 = *(const float4*)ap;
                float4 f1 = *(const float4*)(ap + 4);
                a[i][0] = (_Float16)f0.x; a[i][1] = (_Float16)f0.y;
                a[i][2] = (_Float16)f0.z; a[i][3] = (_Float16)f0.w;
                a[i][4] = (_Float16)f1.x; a[i][5] = (_Float16)f1.y;
                a[i][6] = (_Float16)f1.z; a[i][7] = (_Float16)f1.w;
            }
        }
        #pragma unroll
        for (int j = 0; j < NT; ++j)
            b[j] = *(const half8*)(Bt + (size_t)brow[j] * K + kk + quad * 8);
        #pragma unroll
        for (int i = 0; i < 4; ++i)
            #pragma unroll
            for (int j = 0; j < NT; ++j)
                acc[i][j] = __builtin_amdgcn_mfma_f32_16x16x32_f16(a[i], b[j], acc[i][j], 0, 0, 0);
    }
    #pragma unroll
    for (int i = 0; i < 4; ++i) {
        #pragma unroll
        for (int r = 0; r < 4; ++r) {
            int row = m0 + wm * 64 + i * 16 + quad * 4 + r;
            if (row < M) {
                #pragma unroll
                for (int j = 0; j < NT; ++j)
                    C[(size_t)row * N + n0 + wn * NT * 16 + j * 16 + lr] =
                        (_Float16)acc[i][j][r];
            }
        }
    }
    if constexpr (ELR == 1) {
        int h = n0 / 64 + wn;
        float alh[NT], arh[NT];
        #pragma unroll
        for (int j = 0; j < NT; ++j) {
            alh[j] = al[h * 64 + j * 16 + lr];
            arh[j] = ar[h * 64 + j * 16 + lr];
        }
        #pragma unroll
        for (int i = 0; i < 4; ++i) {
            #pragma unroll
            for (int r = 0; r < 4; ++r) {
                float pel = 0.f, per = 0.f;
                #pragma unroll
                for (int j = 0; j < NT; ++j) {
                    pel = fmaf(acc[i][j][r], alh[j], pel);
                    per = fmaf(acc[i][j][r], arh[j], per);
                }
                #pragma unroll
                for (int o = 1; o < 16; o <<= 1) {
                    pel += __shfl_xor(pel, o);
                    per += __shfl_xor(per, o);
                }
                if (lr == 0) {
                    int row = m0 + wm * 64 + i * 16 + quad * 4 + r;
                    if (row < M) {
                        el[(size_t)row * 4 + h] = pel;   // node-major [M][4]
                        er[(size_t)row * 4 + h] = per;
                    }
                }
            }
        }
    }
    if constexpr (ELR == 2) {
        __shared__ float elbuf[128], erbuf[128];
        float alv[NT], arv[NT];
        #pragma unroll
        for (int j = 0; j < NT; ++j) {
            alv[j] = al[wn * NT * 16 + j * 16 + lr];
            arv[j] = ar[wn * NT * 16 + j * 16 + lr];
        }
        float pel_s[4][4], per_s[4][4];
        #pragma unroll
        for (int i = 0; i < 4; ++i) {
            #pragma unroll
            for (int r = 0; r < 4; ++r) {
                float pel = 0.f, per = 0.f;
                #pragma unroll
                for (int j = 0; j < NT; ++j) {
                    pel = fmaf(acc[i][j][r], alv[j], pel);
                    per = fmaf(acc[i][j][r], arv[j], per);
                }
                #pragma unroll
                for (int o = 1; o < 16; o <<= 1) {
                    pel += __shfl_xor(pel, o);
                    per += __shfl_xor(per, o);
                }
                pel_s[i][r] = pel; per_s[i][r] = per;
            }
        }
        if (wn == 1 && lr == 0) {
            #pragma unroll
            for (int i = 0; i < 4; ++i)
                #pragma unroll
                for (int r = 0; r < 4; ++r) {
                    int rl = wm * 64 + i * 16 + quad * 4 + r;
                    elbuf[rl] = pel_s[i][r];
                    erbuf[rl] = per_s[i][r];
                }
        }
        __syncthreads();
        if (wn == 0 && lr == 0) {
            #pragma unroll
            for (int i = 0; i < 4; ++i)
                #pragma unroll
                for (int r = 0; r < 4; ++r) {
                    int rl = wm * 64 + i * 16 + quad * 4 + r;
                    int row = m0 + rl;
                    if (row < M) {
                        el[row] = pel_s[i][r] + elbuf[rl];
                        er[row] = per_s[i][r] + erbuf[rl];
                    }
                }
        }
    }
}

// ---------------- fused softmax + weighted aggregation (layer 1) ----------
// R21: Duff's-device load cascade. R20 post-mortem: wave-uniform guards cut
// requests (102->82us) but made each slot a scalar-branch block -> serial
// per-slot round trips (~21k-cy lifetime by Little's law). switch(nst) with
// fallthrough issues exactly nst ssorted loads back-to-back (1 RT), then
// all nst el+feat loads back-to-back (1 RT), then VALU-only consume.
// Minimal issue (R20) + parallel issue (R18). Fast path deg<=24 (12 slots
// x 2 edges, 97.8% of Poisson(16) nodes); R20 loop as fallback.

__global__ __launch_bounds__(256) void spmm1_kernel(const _Float16* __restrict__ feat,  // [N][256]
                                                    const float* __restrict__ el,  // [N][4]
                                                    const float* __restrict__ er,  // [N][4]
                                                    const int* __restrict__ offs,
                                                    const int* __restrict__ ssorted,
                                                    _Float16* __restrict__ h1) {
    int n = blockIdx.x * 4 + (threadIdx.x >> 6);   // wave = node, all 4 heads
    if (n >= NNODES) return;
    int l = threadIdx.x & 63;
    int p2 = l >> 5;              // edge-pair half (2 edges per VMEM)
    int q  = l & 31;              // 32 lanes cover 512B = 4 heads x 64 dims
    int h  = q >> 3;              // this lane's head
    int start = offs[n], end = offs[n + 1];
    int rem = end - start;
    float ern = er[(size_t)n * 4 + h];
    const half8* f8 = (const half8*)feat;   // node stride 32 half8
    float acc[8];
    #pragma unroll
    for (int i = 0; i < 8; ++i) acc[i] = 0.f;
    float ws = 0.f;
    if (rem <= 24) {
        int nst = (rem + 1) >> 1;             // active slots, 0..12
        int sjv[12]; float elv[12]; half8 fr[12];
        switch (nst) {                        // phase 1: all ssorted in flight
        case 12: { int x = start + 22 + p2; sjv[11] = ssorted[x < end ? x : start]; }
        case 11: { int x = start + 20 + p2; sjv[10] = ssorted[x < end ? x : start]; }
        case 10: { int x = start + 18 + p2; sjv[9]  = ssorted[x < end ? x : start]; }
        case 9:  { int x = start + 16 + p2; sjv[8]  = ssorted[x < end ? x : start]; }
        case 8:  { int x = start + 14 + p2; sjv[7]  = ssorted[x < end ? x : start]; }
        case 7:  { int x = start + 12 + p2; sjv[6]  = ssorted[x < end ? x : start]; }
        case 6:  { int x = start + 10 + p2; sjv[5]  = ssorted[x < end ? x : start]; }
        case 5:  { int x = start + 8  + p2; sjv[4]  = ssorted[x < end ? x : start]; }
        case 4:  { int x = start + 6  + p2; sjv[3]  = ssorted[x < end ? x : start]; }
        case 3:  { int x = start + 4  + p2; sjv[2]  = ssorted[x < end ? x : start]; }
        case 2:  { int x = start + 2  + p2; sjv[1]  = ssorted[x < end ? x : start]; }
        case 1:  { int x = start + 0  + p2; sjv[0]  = ssorted[x < end ? x : start]; }
        default: break;
        }
        switch (nst) {                        // phase 2: all el+feat in flight
        case 12: { int s = sjv[11]; elv[11] = el[(size_t)s * 4 + h]; fr[11] = f8[(size_t)s * 32 + q]; }
        case 11: { int s = sjv[10]; elv[10] = el[(size_t)s * 4 + h]; fr[10] = f8[(size_t)s * 32 + q]; }
        case 10: { int s = sjv[9];  elv[9]  = el[(size_t)s * 4 + h]; fr[9]  = f8[(size_t)s * 32 + q]; }
        case 9:  { int s = sjv[8];  elv[8]  = el[(size_t)s * 4 + h]; fr[8]  = f8[(size_t)s * 32 + q]; }
        case 8:  { int s = sjv[7];  elv[7]  = el[(size_t)s * 4 + h]; fr[7]  = f8[(size_t)s * 32 + q]; }
        case 7:  { int s = sjv[6];  elv[6]  = el[(size_t)s * 4 + h]; fr[6]  = f8[(size_t)s * 32 + q]; }
        case 6:  { int s = sjv[5];  elv[5]  = el[(size_t)s * 4 + h]; fr[5]  = f8[(size_t)s * 32 + q]; }
        case 5:  { int s = sjv[4];  elv[4]  = el[(size_t)s * 4 + h]; fr[4]  = f8[(size_t)s * 32 + q]; }
        case 4:  { int s = sjv[3];  elv[3]  = el[(size_t)s * 4 + h]; fr[3]  = f8[(size_t)s * 32 + q]; }
        case 3:  { int s = sjv[2];  elv[2]  = el[(size_t)s * 4 + h]; fr[2]  = f8[(size_t)s * 32 + q]; }
        case 2:  { int s = sjv[1];  elv[1]  = el[(size_t)s * 4 + h]; fr[1]  = f8[(size_t)s * 32 + q]; }
        case 1:  { int s = sjv[0];  elv[0]  = el[(size_t)s * 4 + h]; fr[0]  = f8[(size_t)s * 32 + q]; }
        default: break;
        }
        #pragma unroll                        // phase 3: VALU-only consume
        for (int js = 0; js < 12; ++js) {
            if (js < nst) {                   // wave-uniform, no loads inside
                bool vld = (start + js * 2 + p2) < end;
                float ev = elv[js] + ern;
                ev = ev > 0.f ? ev : NEG_SLOPE * ev;
                float w = vld ? __expf(ev) : 0.f;   // no max-sub (safe: |e|<~8)
                ws += w;
                #pragma unroll
                for (int i = 0; i < 8; ++i) acc[i] = fmaf(w, (float)fr[js][i], acc[i]);
            }
        }
    } else {
        // fallback (deg > 24, ~2.2%): R20 guarded dynamic loop
        for (int base = start; base < end; base += 16) {
            #pragma unroll
            for (int js = 0; js < 8; ++js) {
                if (base + js * 2 < end) {
                    int idx = base + js * 2 + p2;
                    bool vld = idx < end;
                    int ic = vld ? idx : start;
                    int sj = ssorted[ic];
                    float ev = el[(size_t)sj * 4 + h] + ern;
                    ev = ev > 0.f ? ev : NEG_SLOPE * ev;
                    float w = vld ? __expf(ev) : 0.f;
                    half8 fv = f8[(size_t)sj * 32 + q];
                    ws += w;
                    #pragma unroll
                    for (int i = 0; i < 8; ++i) acc[i] = fmaf(w, (float)fv[i], acc[i]);
                }
            }
        }
    }
    // fold the two edge-pair halves
    ws += __shfl_xor(ws, 32);
    #pragma unroll
    for (int i = 0; i < 8; ++i) acc[i] += __shfl_xor(acc[i], 32);
    if (l < 32) {
        float inv = ws > 0.f ? 1.f / ws : 0.f;
        half8 hv;
        #pragma unroll
        for (int i = 0; i < 8; ++i) {
            float v = acc[i] * inv;
            v = v > 0.f ? v : __expf(v) - 1.f;   // ELU
            hv[i] = (_Float16)v;
        }
        *(half8*)&h1[(size_t)n * 256 + q * 8] = hv;    // 512B/node contiguous
    }
}

// ---------------- fused softmax + weighted aggregation (layer 2) ----------
// Single head, 64 dims, fp32 out. Same Duff cascade: 4 slots x 8 edges,
// fast path deg<=32 (99.98%).

__global__ __launch_bounds__(256) void spmm2_kernel(const _Float16* __restrict__ feat,
                                                    const float* __restrict__ el,
                                                    const float* __restrict__ er,
                                                    const int* __restrict__ offs,
                                                    const int* __restrict__ ssorted,
                                                    float* __restrict__ out) {
    int n = blockIdx.x * 4 + (threadIdx.x >> 6);
    if (n >= NNODES) return;
    int l = threadIdx.x & 63;
    int e8 = l >> 3, li = l & 7;
    int start = offs[n], end = offs[n + 1];
    int rem = end - start;
    float ern = er[n];
    const half8* f8 = (const half8*)feat;   // node stride 8 half8s
    float acc[8];
    #pragma unroll
    for (int i = 0; i < 8; ++i) acc[i] = 0.f;
    float ws = 0.f;
    if (rem <= 32) {
        int nst = (rem + 7) >> 3;             // active slots, 0..4
        int sjv[4]; float elv[4]; half8 fr[4];
        switch (nst) {                        // phase 1: ssorted
        case 4: { int x = start + 24 + e8; sjv[3] = ssorted[x < end ? x : start]; }
        case 3: { int x = start + 16 + e8; sjv[2] = ssorted[x < end ? x : start]; }
        case 2: { int x = start + 8  + e8; sjv[1] = ssorted[x < end ? x : start]; }
        case 1: { int x = start + 0  + e8; sjv[0] = ssorted[x < end ? x : start]; }
        default: break;
        }
        switch (nst) {                        // phase 2: el + feat
        case 4: { int s = sjv[3]; elv[3] = el[s]; fr[3] = f8[(size_t)s * 8 + li]; }
        case 3: { int s = sjv[2]; elv[2] = el[s]; fr[2] = f8[(size_t)s * 8 + li]; }
        case 2: { int s = sjv[1]; elv[1] = el[s]; fr[1] = f8[(size_t)s * 8 + li]; }
        case 1: { int s = sjv[0]; elv[0] = el[s]; fr[0] = f8[(size_t)s * 8 + li]; }
        default: break;
        }
        #pragma unroll                        // phase 3: consume
        for (int js = 0; js < 4; ++js) {
            if (js < nst) {
                bool vld = (start + js * 8 + e8) < end;
                float ev = elv[js] + ern;
                ev = ev > 0.f ? ev : NEG_SLOPE * ev;
                float w = vld ? __expf(ev) : 0.f;
                ws += w;
                #pragma unroll
                for (int i = 0; i < 8; ++i) acc[i] = fmaf(w, (float)fr[js][i], acc[i]);
            }
        }
    } else {
        for (int base = start; base < end; base += 32) {
            #pragma unroll
            for (int js = 0; js < 4; ++js) {
                if (base + js * 8 < end) {
                    int idx = base + js * 8 + e8;
                    bool vld = idx < end;
                    int ic = vld ? idx : start;
                    int sj = ssorted[ic];
                    float ev = el[sj] + ern;
                    ev = ev > 0.f ? ev : NEG_SLOPE * ev;
                    float w = vld ? __expf(ev) : 0.f;
                    half8 fv = f8[(size_t)sj * 8 + li];
                    ws += w;
                    #pragma unroll
                    for (int i = 0; i < 8; ++i) acc[i] = fmaf(w, (float)fv[i], acc[i]);
                }
            }
        }
    }
    #pragma unroll
    for (int o = 8; o < 64; o <<= 1) {
        ws += __shfl_xor(ws, o);
        #pragma unroll
        for (int i = 0; i < 8; ++i) acc[i] += __shfl_xor(acc[i], o);
    }
    if (e8 == 0) {
        float inv = ws > 0.f ? 1.f / ws : 0.f;
        float4 o0, o1;
        o0.x = acc[0] * inv; o0.y = acc[1] * inv;
        o0.z = acc[2] * inv; o0.w = acc[3] * inv;
        o1.x = acc[4] * inv; o1.y = acc[5] * inv;
        o1.z = acc[6] * inv; o1.w = acc[7] * inv;
        float4* op = (float4*)(out + (size_t)n * 64 + li * 8);
        op[0] = o0; op[1] = o1;
    }
}

// ---------------- launch ----------------

extern "C" void kernel_launch(void* const* d_in, const int* in_sizes, int n_in,
                              void* d_out, int out_size, void* d_ws, size_t ws_size,
                              hipStream_t stream) {
    const float* x   = (const float*)d_in[0];
    const int*   src = (const int*)d_in[1];
    const int*   dst = (const int*)d_in[2];
    const float* W1  = (const float*)d_in[3];
    const float* al1 = (const float*)d_in[4];
    const float* ar1 = (const float*)d_in[5];
    const float* W2  = (const float*)d_in[6];
    const float* al2 = (const float*)d_in[7];
    const float* ar2 = (const float*)d_in[8];
    float* out = (float*)d_out;

    char* ws = (char*)d_ws;
    size_t off = 0;
    auto alloc = [&](size_t bytes) -> void* {
        void* p = ws + off;
        off += (bytes + 255) & ~(size_t)255;
        return p;
    };
    _Float16* feat1 = (_Float16*)alloc((size_t)NNODES * 256 * 2);   // node-major [N][256]
    _Float16* h1    = (_Float16*)alloc((size_t)NNODES * 256 * 2);   // node-major [N][256]
    _Float16* W1t   = (_Float16*)alloc((size_t)256 * 256 * 2);
    _Float16* W2t   = (_Float16*)alloc((size_t)64 * 256 * 2);
    float* el1    = (float*)alloc((size_t)NNODES * 4 * 4);          // node-major [N][4]
    float* er1    = (float*)alloc((size_t)NNODES * 4 * 4);
    float* el2    = (float*)alloc((size_t)NNODES * 4);
    float* er2    = (float*)alloc((size_t)NNODES * 4);
    int* deg      = (int*)alloc((size_t)NNODES * 4);
    int* cursor   = (int*)alloc((size_t)NNODES * 4);
    int* offs     = (int*)alloc((size_t)(NNODES + 1) * 4);
    int* bsums    = (int*)alloc((size_t)NB * 4);
    int* ssorted  = (int*)alloc((size_t)NEDGES * 4);
    _Float16* feat2 = feat1;   // feat1 dead after spmm1; reuse for layer 2

    // --- CSR build ---
    hipMemsetAsync(deg, 0, (size_t)NNODES * 4, stream);
    hipMemsetAsync(cursor, 0, (size_t)NNODES * 4, stream);
    hist_kernel<<<(NEDGES + 255) / 256, 256, 0, stream>>>(dst, deg);
    bsum_kernel<<<NB, 256, 0, stream>>>(deg, bsums);
    scan_write_kernel<<<NB, 256, 0, stream>>>(deg, bsums, offs);
    scatter_kernel<<<(NEDGES + 255) / 256, 256, 0, stream>>>(src, dst, offs, cursor, ssorted);

    // --- weight conversions (single launch) ---
    convert_wt_kernel<<<(256 * 256 + 256 * 64 + 255) / 256, 256, 0, stream>>>(
        W1, W1t, W2, W2t);

    // --- Layer 1: GEMM (node-major feat + el/er); all-heads fused SpMM ---
    gemm_f16_kernel<128, false, 1><<<dim3(256 / 128, (NNODES + 127) / 128), 256, 0, stream>>>(
        x, nullptr, W1t, feat1, al1, ar1, el1, er1, NNODES, 256);
    spmm1_kernel<<<(NNODES + 3) / 4, 256, 0, stream>>>(
        feat1, el1, er1, offs, ssorted, h1);

    // --- Layer 2: fp16 GEMM + fused single-head el/er; fused-softmax SpMM ---
    gemm_f16_kernel<64, true, 2><<<dim3(64 / 64, (NNODES + 127) / 128), 256, 0, stream>>>(
        nullptr, h1, W2t, feat2, al2, ar2, el2, er2, NNODES, 64);
    spmm2_kernel<<<(NNODES + 3) / 4, 256, 0, stream>>>(
        feat2, el2, er2, offs, ssorted, out);
}

// Round 11
// 338.397 us; speedup vs baseline: 1.1072x; 1.1072x over previous
//
#include <hip/hip_runtime.h>
#include <math.h>

#define NNODES 50000
#define NEDGES 800000
#define INDIM 256
#define HID 64
#define HEADS 4
#define OUTDIM 64
#define NEG_SLOPE 0.2f
#define NB ((NNODES + 1023) / 1024)   // 49 scan blocks

typedef __attribute__((ext_vector_type(4))) float f32x4;
typedef _Float16 __attribute__((ext_vector_type(8))) half8;

// ---------------- CSR build ----------------

__global__ __launch_bounds__(256) void hist_kernel(const int* __restrict__ dst,
                                                   int* __restrict__ deg) {
    int i = blockIdx.x * 256 + threadIdx.x;
    if (i < NEDGES) atomicAdd(&deg[dst[i]], 1);
}

__global__ __launch_bounds__(256) void bsum_kernel(const int* __restrict__ deg,
                                                   int* __restrict__ bsums) {
    int b = blockIdx.x, t = threadIdx.x;
    int base = b * 1024 + t * 4;
    int s = 0;
    #pragma unroll
    for (int e = 0; e < 4; ++e) { int i = base + e; if (i < NNODES) s += deg[i]; }
    #pragma unroll
    for (int o = 32; o; o >>= 1) s += __shfl_xor(s, o);
    __shared__ int ws[4];
    int lane = t & 63, wid = t >> 6;
    if (lane == 0) ws[wid] = s;
    __syncthreads();
    if (t == 0) bsums[b] = ws[0] + ws[1] + ws[2] + ws[3];
}

__global__ __launch_bounds__(256) void scan_write_kernel(const int* __restrict__ deg,
                                                         const int* __restrict__ bsums,
                                                         int* __restrict__ offs) {
    int b = blockIdx.x, t = threadIdx.x;
    int lane = t & 63, wid = t >> 6;
    int bv = (lane < b) ? bsums[lane] : 0;    // b <= NB-1 < 64
    #pragma unroll
    for (int o = 32; o; o >>= 1) bv += __shfl_xor(bv, o);  // block global offset
    int base = b * 1024 + t * 4;
    int v[4]; int tsum = 0;
    #pragma unroll
    for (int e = 0; e < 4; ++e) {
        int i = base + e;
        v[e] = (i < NNODES) ? deg[i] : 0;
        tsum += v[e];
    }
    int p = tsum;
    #pragma unroll
    for (int o = 1; o < 64; o <<= 1) { int u = __shfl_up(p, o); if (lane >= o) p += u; }
    __shared__ int ws[4];
    if (lane == 63) ws[wid] = p;
    __syncthreads();
    int woff = 0;
    for (int i = 0; i < wid; ++i) woff += ws[i];
    int run = bv + woff + p - tsum;           // exclusive prefix for this thread
    #pragma unroll
    for (int e = 0; e < 4; ++e) {
        int i = base + e;
        if (i < NNODES) { offs[i] = run; run += v[e]; }
    }
    if (b == 0 && t == 0) offs[NNODES] = NEDGES;
}

__global__ __launch_bounds__(256) void scatter_kernel(const int* __restrict__ src,
                                                      const int* __restrict__ dst,
                                                      const int* __restrict__ offs,
                                                      int* __restrict__ cursor,
                                                      int* __restrict__ ssorted) {
    int i = blockIdx.x * 256 + threadIdx.x;
    if (i < NEDGES) {
        int d = dst[i];
        int pos = offs[d] + atomicAdd(&cursor[d], 1);
        ssorted[pos] = src[i];
    }
}

// ---------------- weight transpose -> fp16 (both weights, one launch) ----

__global__ __launch_bounds__(256) void convert_wt_kernel(const float* __restrict__ W1,
                                                         _Float16* __restrict__ W1t,
                                                         const float* __restrict__ W2,
                                                         _Float16* __restrict__ W2t) {
    int idx = blockIdx.x * 256 + threadIdx.x;
    if (idx < 256 * 256) {
        int k = idx >> 8, n = idx & 255;
        W1t[n * 256 + k] = (_Float16)W1[idx];
    } else if (idx < 256 * 256 + 256 * 64) {
        int j = idx - 256 * 256;
        int k = j >> 6, n = j & 63;
        W2t[n * 256 + k] = (_Float16)W2[j];
    }
}

// ---------------- fp16 MFMA GEMM, LDS-free, 128x(BN) tile ----------------
// ELR=1 (BN=128): C node-major [M][256]; el/er NODE-MAJOR [M][4] so spmm1
//   reads all 4 heads' el with one 4B/lane gather off the same line.
// ELR=2 (BN=64): single head; per-wn partial dot + 1KB LDS combine.

template <int BN, bool AFP16, int ELR>
__global__ __launch_bounds__(256) void gemm_f16_kernel(
        const float* __restrict__ Af, const _Float16* __restrict__ Ah,
        const _Float16* __restrict__ Bt,
        _Float16* __restrict__ C,
        const float* __restrict__ al, const float* __restrict__ ar,
        float* __restrict__ el, float* __restrict__ er,
        int M, int N) {
    constexpr int K = 256;
    constexpr int NT = BN / 32;       // 16-wide n-tiles per wave
    int t = threadIdx.x;
    int lane = t & 63, w = t >> 6;
    int wm = w >> 1, wn = w & 1;
    int lr = lane & 15, quad = lane >> 4;
    int m0 = blockIdx.y * 128, n0 = blockIdx.x * BN;

    f32x4 acc[4][NT];
    #pragma unroll
    for (int i = 0; i < 4; ++i)
        #pragma unroll
        for (int j = 0; j < NT; ++j) acc[i][j] = (f32x4){0.f, 0.f, 0.f, 0.f};

    int arow[4];
    #pragma unroll
    for (int i = 0; i < 4; ++i) {
        int r = m0 + wm * 64 + i * 16 + lr;
        arow[i] = (r < M) ? r : (M - 1);
    }
    int brow[NT];
    #pragma unroll
    for (int j = 0; j < NT; ++j) brow[j] = n0 + wn * NT * 16 + j * 16 + lr;

    #pragma unroll
    for (int kk = 0; kk < K; kk += 32) {
        half8 a[4], b[NT];
        if (AFP16) {
            #pragma unroll
            for (int i = 0; i < 4; ++i)
                a[i] = *(const half8*)(Ah + (size_t)arow[i] * K + kk + quad * 8);
        } else {
            #pragma unroll
            for (int i = 0; i < 4; ++i) {
                const float* ap = Af + (size_t)arow[i] * K + kk + quad * 8;
                float4 f0 = *(const float4*)ap;
                float4 f1 = *(const float4*)(ap + 4);
                a[i][0] = (_Float16)f0.x; a[i][1] = (_Float16)f0.y;
                a[i][2] = (_Float16)f0.z; a[i][3] = (_Float16)f0.w;
                a[i][4] = (_Float16)f1.x; a[i][5] = (_Float16)f1.y;
                a[i][6] = (_Float16)f1.z; a[i][7] = (_Float16)f1.w;
            }
        }
        #pragma unroll
        for (int j = 0; j < NT; ++j)
            b[j] = *(const half8*)(Bt + (size_t)brow[j] * K + kk + quad * 8);
        #pragma unroll
        for (int i = 0; i < 4; ++i)
            #pragma unroll
            for (int j = 0; j < NT; ++j)
                acc[i][j] = __builtin_amdgcn_mfma_f32_16x16x32_f16(a[i], b[j], acc[i][j], 0, 0, 0);
    }
    #pragma unroll
    for (int i = 0; i < 4; ++i) {
        #pragma unroll
        for (int r = 0; r < 4; ++r) {
            int row = m0 + wm * 64 + i * 16 + quad * 4 + r;
            if (row < M) {
                #pragma unroll
                for (int j = 0; j < NT; ++j)
                    C[(size_t)row * N + n0 + wn * NT * 16 + j * 16 + lr] =
                        (_Float16)acc[i][j][r];
            }
        }
    }
    if constexpr (ELR == 1) {
        int h = n0 / 64 + wn;
        float alh[NT], arh[NT];
        #pragma unroll
        for (int j = 0; j < NT; ++j) {
            alh[j] = al[h * 64 + j * 16 + lr];
            arh[j] = ar[h * 64 + j * 16 + lr];
        }
        #pragma unroll
        for (int i = 0; i < 4; ++i) {
            #pragma unroll
            for (int r = 0; r < 4; ++r) {
                float pel = 0.f, per = 0.f;
                #pragma unroll
                for (int j = 0; j < NT; ++j) {
                    pel = fmaf(acc[i][j][r], alh[j], pel);
                    per = fmaf(acc[i][j][r], arh[j], per);
                }
                #pragma unroll
                for (int o = 1; o < 16; o <<= 1) {
                    pel += __shfl_xor(pel, o);
                    per += __shfl_xor(per, o);
                }
                if (lr == 0) {
                    int row = m0 + wm * 64 + i * 16 + quad * 4 + r;
                    if (row < M) {
                        el[(size_t)row * 4 + h] = pel;   // node-major [M][4]
                        er[(size_t)row * 4 + h] = per;
                    }
                }
            }
        }
    }
    if constexpr (ELR == 2) {
        __shared__ float elbuf[128], erbuf[128];
        float alv[NT], arv[NT];
        #pragma unroll
        for (int j = 0; j < NT; ++j) {
            alv[j] = al[wn * NT * 16 + j * 16 + lr];
            arv[j] = ar[wn * NT * 16 + j * 16 + lr];
        }
        float pel_s[4][4], per_s[4][4];
        #pragma unroll
        for (int i = 0; i < 4; ++i) {
            #pragma unroll
            for (int r = 0; r < 4; ++r) {
                float pel = 0.f, per = 0.f;
                #pragma unroll
                for (int j = 0; j < NT; ++j) {
                    pel = fmaf(acc[i][j][r], alv[j], pel);
                    per = fmaf(acc[i][j][r], arv[j], per);
                }
                #pragma unroll
                for (int o = 1; o < 16; o <<= 1) {
                    pel += __shfl_xor(pel, o);
                    per += __shfl_xor(per, o);
                }
                pel_s[i][r] = pel; per_s[i][r] = per;
            }
        }
        if (wn == 1 && lr == 0) {
            #pragma unroll
            for (int i = 0; i < 4; ++i)
                #pragma unroll
                for (int r = 0; r < 4; ++r) {
                    int rl = wm * 64 + i * 16 + quad * 4 + r;
                    elbuf[rl] = pel_s[i][r];
                    erbuf[rl] = per_s[i][r];
                }
        }
        __syncthreads();
        if (wn == 0 && lr == 0) {
            #pragma unroll
            for (int i = 0; i < 4; ++i)
                #pragma unroll
                for (int r = 0; r < 4; ++r) {
                    int rl = wm * 64 + i * 16 + quad * 4 + r;
                    int row = m0 + rl;
                    if (row < M) {
                        el[row] = pel_s[i][r] + elbuf[rl];
                        er[row] = per_s[i][r] + erbuf[rl];
                    }
                }
        }
    }
}

// ---------------- fused softmax + weighted aggregation (layer 1) ----------
// R22: depth-2 software pipeline at R20's register budget. R21 lesson:
// parallel issue works (lifetime 21k->15k cy) but fr[12] cost 44 VGPR ->
// occ 43% -> net loss. Rotation: while consuming slot j (A regs), issue
// slot j+1's el/feat (B regs, sj already fetched) and slot j+2's ssorted.
// Per-slot serial cost ~2 RT -> ~1 RT; +12 VGPR only (~32 total).
// Handles any degree - no fallback path.

__global__ __launch_bounds__(256) void spmm1_kernel(const _Float16* __restrict__ feat,  // [N][256]
                                                    const float* __restrict__ el,  // [N][4]
                                                    const float* __restrict__ er,  // [N][4]
                                                    const int* __restrict__ offs,
                                                    const int* __restrict__ ssorted,
                                                    _Float16* __restrict__ h1) {
    int n = blockIdx.x * 4 + (threadIdx.x >> 6);   // wave = node, all 4 heads
    if (n >= NNODES) return;
    int l = threadIdx.x & 63;
    int p2 = l >> 5;              // edge-pair half (2 edges per VMEM)
    int q  = l & 31;              // 32 lanes cover 512B = 4 heads x 64 dims
    int h  = q >> 3;              // this lane's head
    int start = offs[n], end = offs[n + 1];
    int nst = (end - start + 1) >> 1;   // 2-edge slots
    float ern = er[(size_t)n * 4 + h];
    const half8* f8 = (const half8*)feat;   // node stride 32 half8
    float acc[8];
    #pragma unroll
    for (int i = 0; i < 8; ++i) acc[i] = 0.f;
    float ws = 0.f;
    half8 z;
    #pragma unroll
    for (int i = 0; i < 8; ++i) z[i] = (_Float16)0;
    int sjB = 0, sjN = 0;
    float elA = 0.f, elB = 0.f;
    half8 fvA = z, fvB = z;
    if (nst > 0) {                 // prologue: slot0 chain + slot1 sj in flight
        int x0 = start + p2;
        int sjA = ssorted[x0 < end ? x0 : start];
        if (nst > 1) {
            int x1 = start + 2 + p2;
            sjB = ssorted[x1 < end ? x1 : start];
        }
        elA = el[(size_t)sjA * 4 + h];
        fvA = f8[(size_t)sjA * 32 + q];
    }
    for (int js = 0; js < nst; ++js) {
        if (js + 1 < nst) {        // issue next slot's el/feat (sj ready)
            elB = el[(size_t)sjB * 4 + h];
            fvB = f8[(size_t)sjB * 32 + q];
        }
        if (js + 2 < nst) {        // issue next-next slot's sj
            int x = start + (js + 2) * 2 + p2;
            sjN = ssorted[x < end ? x : start];
        }
        // consume slot js (A regs; waits only on loads issued last iteration)
        bool vld = (start + js * 2 + p2) < end;
        float ev = elA + ern;
        ev = ev > 0.f ? ev : NEG_SLOPE * ev;
        float w = vld ? __expf(ev) : 0.f;    // no max-sub (safe: |e|<~8)
        ws += w;
        #pragma unroll
        for (int i = 0; i < 8; ++i) acc[i] = fmaf(w, (float)fvA[i], acc[i]);
        elA = elB; fvA = fvB; sjB = sjN;     // rotate
    }
    // fold the two edge-pair halves
    ws += __shfl_xor(ws, 32);
    #pragma unroll
    for (int i = 0; i < 8; ++i) acc[i] += __shfl_xor(acc[i], 32);
    if (l < 32) {
        float inv = ws > 0.f ? 1.f / ws : 0.f;
        half8 hv;
        #pragma unroll
        for (int i = 0; i < 8; ++i) {
            float v = acc[i] * inv;
            v = v > 0.f ? v : __expf(v) - 1.f;   // ELU
            hv[i] = (_Float16)v;
        }
        *(half8*)&h1[(size_t)n * 256 + q * 8] = hv;    // 512B/node contiguous
    }
}

// ---------------- fused softmax + weighted aggregation (layer 2) ----------
// Single head, 64 dims, fp32 out. Same depth-2 rotation (slots of 8 edges).

__global__ __launch_bounds__(256) void spmm2_kernel(const _Float16* __restrict__ feat,
                                                    const float* __restrict__ el,
                                                    const float* __restrict__ er,
                                                    const int* __restrict__ offs,
                                                    const int* __restrict__ ssorted,
                                                    float* __restrict__ out) {
    int n = blockIdx.x * 4 + (threadIdx.x >> 6);
    if (n >= NNODES) return;
    int l = threadIdx.x & 63;
    int e8 = l >> 3, li = l & 7;
    int start = offs[n], end = offs[n + 1];
    int nst = (end - start + 7) >> 3;   // 8-edge slots
    float ern = er[n];
    const half8* f8 = (const half8*)feat;   // node stride 8 half8s
    float acc[8];
    #pragma unroll
    for (int i = 0; i < 8; ++i) acc[i] = 0.f;
    float ws = 0.f;
    half8 z;
    #pragma unroll
    for (int i = 0; i < 8; ++i) z[i] = (_Float16)0;
    int sjB = 0, sjN = 0;
    float elA = 0.f, elB = 0.f;
    half8 fvA = z, fvB = z;
    if (nst > 0) {
        int x0 = start + e8;
        int sjA = ssorted[x0 < end ? x0 : start];
        if (nst > 1) {
            int x1 = start + 8 + e8;
            sjB = ssorted[x1 < end ? x1 : start];
        }
        elA = el[sjA];
        fvA = f8[(size_t)sjA * 8 + li];
    }
    for (int js = 0; js < nst; ++js) {
        if (js + 1 < nst) {
            elB = el[sjB];
            fvB = f8[(size_t)sjB * 8 + li];
        }
        if (js + 2 < nst) {
            int x = start + (js + 2) * 8 + e8;
            sjN = ssorted[x < end ? x : start];
        }
        bool vld = (start + js * 8 + e8) < end;
        float ev = elA + ern;
        ev = ev > 0.f ? ev : NEG_SLOPE * ev;
        float w = vld ? __expf(ev) : 0.f;
        ws += w;
        #pragma unroll
        for (int i = 0; i < 8; ++i) acc[i] = fmaf(w, (float)fvA[i], acc[i]);
        elA = elB; fvA = fvB; sjB = sjN;
    }
    #pragma unroll
    for (int o = 8; o < 64; o <<= 1) {
        ws += __shfl_xor(ws, o);
        #pragma unroll
        for (int i = 0; i < 8; ++i) acc[i] += __shfl_xor(acc[i], o);
    }
    if (e8 == 0) {
        float inv = ws > 0.f ? 1.f / ws : 0.f;
        float4 o0, o1;
        o0.x = acc[0] * inv; o0.y = acc[1] * inv;
        o0.z = acc[2] * inv; o0.w = acc[3] * inv;
        o1.x = acc[4] * inv; o1.y = acc[5] * inv;
        o1.z = acc[6] * inv; o1.w = acc[7] * inv;
        float4* op = (float4*)(out + (size_t)n * 64 + li * 8);
        op[0] = o0; op[1] = o1;
    }
}

// ---------------- launch ----------------

extern "C" void kernel_launch(void* const* d_in, const int* in_sizes, int n_in,
                              void* d_out, int out_size, void* d_ws, size_t ws_size,
                              hipStream_t stream) {
    const float* x   = (const float*)d_in[0];
    const int*   src = (const int*)d_in[1];
    const int*   dst = (const int*)d_in[2];
    const float* W1  = (const float*)d_in[3];
    const float* al1 = (const float*)d_in[4];
    const float* ar1 = (const float*)d_in[5];
    const float* W2  = (const float*)d_in[6];
    const float* al2 = (const float*)d_in[7];
    const float* ar2 = (const float*)d_in[8];
    float* out = (float*)d_out;

    char* ws = (char*)d_ws;
    size_t off = 0;
    auto alloc = [&](size_t bytes) -> void* {
        void* p = ws + off;
        off += (bytes + 255) & ~(size_t)255;
        return p;
    };
    _Float16* feat1 = (_Float16*)alloc((size_t)NNODES * 256 * 2);   // node-major [N][256]
    _Float16* h1    = (_Float16*)alloc((size_t)NNODES * 256 * 2);   // node-major [N][256]
    _Float16* W1t   = (_Float16*)alloc((size_t)256 * 256 * 2);
    _Float16* W2t   = (_Float16*)alloc((size_t)64 * 256 * 2);
    float* el1    = (float*)alloc((size_t)NNODES * 4 * 4);          // node-major [N][4]
    float* er1    = (float*)alloc((size_t)NNODES * 4 * 4);
    float* el2    = (float*)alloc((size_t)NNODES * 4);
    float* er2    = (float*)alloc((size_t)NNODES * 4);
    int* deg      = (int*)alloc((size_t)NNODES * 4);
    int* cursor   = (int*)alloc((size_t)NNODES * 4);
    int* offs     = (int*)alloc((size_t)(NNODES + 1) * 4);
    int* bsums    = (int*)alloc((size_t)NB * 4);
    int* ssorted  = (int*)alloc((size_t)NEDGES * 4);
    _Float16* feat2 = feat1;   // feat1 dead after spmm1; reuse for layer 2

    // --- CSR build ---
    hipMemsetAsync(deg, 0, (size_t)NNODES * 4, stream);
    hipMemsetAsync(cursor, 0, (size_t)NNODES * 4, stream);
    hist_kernel<<<(NEDGES + 255) / 256, 256, 0, stream>>>(dst, deg);
    bsum_kernel<<<NB, 256, 0, stream>>>(deg, bsums);
    scan_write_kernel<<<NB, 256, 0, stream>>>(deg, bsums, offs);
    scatter_kernel<<<(NEDGES + 255) / 256, 256, 0, stream>>>(src, dst, offs, cursor, ssorted);

    // --- weight conversions (single launch) ---
    convert_wt_kernel<<<(256 * 256 + 256 * 64 + 255) / 256, 256, 0, stream>>>(
        W1, W1t, W2, W2t);

    // --- Layer 1: GEMM (node-major feat + el/er); all-heads fused SpMM ---
    gemm_f16_kernel<128, false, 1><<<dim3(256 / 128, (NNODES + 127) / 128), 256, 0, stream>>>(
        x, nullptr, W1t, feat1, al1, ar1, el1, er1, NNODES, 256);
    spmm1_kernel<<<(NNODES + 3) / 4, 256, 0, stream>>>(
        feat1, el1, er1, offs, ssorted, h1);

    // --- Layer 2: fp16 GEMM + fused single-head el/er; fused-softmax SpMM ---
    gemm_f16_kernel<64, true, 2><<<dim3(64 / 64, (NNODES + 127) / 128), 256, 0, stream>>>(
        nullptr, h1, W2t, feat2, al2, ar2, el2, er2, NNODES, 64);
    spmm2_kernel<<<(NNODES + 3) / 4, 256, 0, stream>>>(
        feat2, el2, er2, offs, ssorted, out);
}